// Round 10
// baseline (178.920 us; speedup 1.0000x reference)
//
#include <hip/hip_runtime.h>
#include <hip/hip_bf16.h>

#define NHEAD 4
#define FIN   768
#define FOUT  64
#define BSZ   4
#define NSEQ  2048
#define BH    (BSZ*NHEAD)
#define LOG2E 1.44269504088896f

typedef __attribute__((ext_vector_type(8)))  short bf16x8;   // MFMA A/B frag
typedef __attribute__((ext_vector_type(16))) float f32x16;   // MFMA 32x32 C/D
typedef __attribute__((ext_vector_type(8)))  unsigned short u16x8;
typedef __attribute__((ext_vector_type(4)))  unsigned short u16x4;
typedef __attribute__((ext_vector_type(4)))  unsigned u32x4;

__device__ __forceinline__ unsigned short f2bf(float f){
  unsigned b = __float_as_uint(f);
  return (unsigned short)((b + 0x7fffu + ((b >> 16) & 1u)) >> 16);
}
__device__ __forceinline__ unsigned fenc(float f){
  unsigned b = __float_as_uint(f);
  return (b & 0x80000000u) ? ~b : (b | 0x80000000u);
}
__device__ __forceinline__ float fdec(unsigned u){
  unsigned b = (u & 0x80000000u) ? (u ^ 0x80000000u) : ~u;
  return __uint_as_float(b);
}
__device__ __forceinline__ float fexp2(float x){
#if __has_builtin(__builtin_amdgcn_exp2f)
  return __builtin_amdgcn_exp2f(x);
#else
  return exp2f(x);
#endif
}
__device__ __forceinline__ unsigned pkbf(float lo, float hi){
#if __has_builtin(__builtin_amdgcn_cvt_pk_bf16_f32)
  typedef __attribute__((ext_vector_type(2))) __bf16 bf2;
  union { bf2 v; unsigned u; } cv;
  cv.v = __builtin_amdgcn_cvt_pk_bf16_f32(lo, hi);
  return cv.u;
#else
  return (unsigned)f2bf(lo) | ((unsigned)f2bf(hi) << 16);
#endif
}

// ---------------------------------------------------------------------------
// Prep: w fp32 -> bf16 swizzled frag image; zeroes dmaxe (so the pipeline is
// idempotent when launched twice).
// ---------------------------------------------------------------------------
__global__ __launch_bounds__(512) void k_prep_w(
    const float* __restrict__ w, unsigned short* __restrict__ wp,
    unsigned* __restrict__ dmaxe)
{
  if (blockIdx.x == 0 && threadIdx.x < BH) dmaxe[threadIdx.x] = 0;
  const int head = blockIdx.x & 3, kt = blockIdx.x >> 2;
  const int o = threadIdx.x & 63, c = threadIdx.x >> 6;   // 512 thr = full panel
  const float* wsrc = w + (size_t)head*FIN*FOUT + (size_t)(kt*64 + c*8)*FOUT + o;
  u16x8 pk;
  #pragma unroll
  for (int j = 0; j < 8; ++j) pk[j] = f2bf(wsrc[(size_t)j*FOUT]);
  *(u16x8*)((char*)wp + ((size_t)((head*12 + kt)*64 + o))*128 + ((c ^ (o & 7)) << 4)) = pk;
}

// ---------------------------------------------------------------------------
// Kernel A (r9 body, unchanged): h' = h @ w_head via 32x32x16 MFMA.
// ---------------------------------------------------------------------------
__global__ __launch_bounds__(512, 2) void k_hprime(
    const float* __restrict__ h, const unsigned short* __restrict__ wp,
    const float* __restrict__ a_src, const float* __restrict__ a_dst,
    unsigned short* __restrict__ hpz2, float* __restrict__ srcv,
    float* __restrict__ dstv, unsigned* __restrict__ dmaxe)
{
  __shared__ __align__(16) char smem[65536];
  float* psumS = (float*)(smem + 16384);
  float* psumD = (float*)(smem + 16896);
  char*  Tt    = smem + 32768;

  const int tid  = threadIdx.x;
  const int bid  = blockIdx.x;
  const int bh1  = (bid & 7) | (((bid >> 3) & 1) << 3);
  const int head = bh1 & 3;
  const int jbase = (bid >> 4) << 6;                 // within-sequence row base
  const int i0a   = (bh1 >> 2)*NSEQ + jbase;         // global flat row
  const int wave = tid >> 6, lane = tid & 63;
  const int wm = wave & 1, wn = (wave >> 1) & 1, kw = wave >> 2;
  const int l32 = lane & 31, h32 = lane >> 5;

  f32x16 acc = {0,0,0,0,0,0,0,0,0,0,0,0,0,0,0,0};

  const int sr = tid >> 3, sc = tid & 7;
  const float* hA = h + (size_t)(i0a + sr)*FIN + sc*8;
  const char*  wB = (const char*)wp + ((size_t)(head*12*64 + sr))*128 + sc*16;
  const int aslot = (sc ^ (sr & 7)) << 4;

  float4 ra0 = *(const float4*)(hA);
  float4 ra1 = *(const float4*)(hA + 4);
  float4 ra2 = *(const float4*)(hA + 64);
  float4 ra3 = *(const float4*)(hA + 68);
  u16x8  rb0 = *(const u16x8*)(wB);
  u16x8  rb1 = *(const u16x8*)(wB + 8192);

  for (int it = 0; it < 6; ++it){
    char* Ab = smem + (it & 1)*16384;
    char* Bb = smem + 32768 + (it & 1)*16384;
    u32x4 pk0, pk1;
    pk0[0] = pkbf(ra0.x, ra0.y); pk0[1] = pkbf(ra0.z, ra0.w);
    pk0[2] = pkbf(ra1.x, ra1.y); pk0[3] = pkbf(ra1.z, ra1.w);
    pk1[0] = pkbf(ra2.x, ra2.y); pk1[1] = pkbf(ra2.z, ra2.w);
    pk1[2] = pkbf(ra3.x, ra3.y); pk1[3] = pkbf(ra3.z, ra3.w);
    *(u32x4*)(Ab + sr*256 + aslot)        = pk0;
    *(u32x4*)(Ab + sr*256 + 128 + aslot)  = pk1;
    *(u16x8*)(Bb + sr*256 + sc*16)        = rb0;
    *(u16x8*)(Bb + sr*256 + 128 + sc*16)  = rb1;
    __syncthreads();
    if (it < 5){
      const float* an = hA + (it+1)*128;
      ra0 = *(const float4*)(an);      ra1 = *(const float4*)(an + 4);
      ra2 = *(const float4*)(an + 64); ra3 = *(const float4*)(an + 68);
      const char* bn = wB + (size_t)(2*(it+1))*8192;
      rb0 = *(const u16x8*)(bn);       rb1 = *(const u16x8*)(bn + 8192);
    }
    #pragma unroll
    for (int s = 0; s < 4; ++s){
      const int slot = (((s*2 + h32) ^ (l32 & 7)) << 4);
      bf16x8 av = *(const bf16x8*)(Ab + (wm*32 + l32)*256 + kw*128 + slot);
      bf16x8 bv = *(const bf16x8*)(Bb + (wn*32 + l32)*256 + kw*128 + slot);
      acc = __builtin_amdgcn_mfma_f32_32x32x16_bf16(av, bv, acc, 0, 0, 0);
    }
    __syncthreads();
  }

  if (kw == 1) *(f32x16*)(smem + (size_t)((wave & 3)*64 + lane)*64) = acc;
  __syncthreads();
  if (kw == 0){
    acc += *(const f32x16*)(smem + (size_t)((wave & 3)*64 + lane)*64);
    const float as = a_src[head*64 + wn*32 + l32];
    const float ad = a_dst[head*64 + wn*32 + l32];
    #pragma unroll
    for (int rb = 0; rb < 4; ++rb){
      const int jb = wm*32 + rb*8 + h32*4;
      u16x4 c4;
      #pragma unroll
      for (int q = 0; q < 4; ++q){
        const float v = acc[rb*4 + q];
        c4[q] = f2bf(v);
        const float t = tanhf(v);
        float ps = t*as, pd = t*ad;
        ps += __shfl_xor(ps, 1);  ps += __shfl_xor(ps, 2);  ps += __shfl_xor(ps, 4);
        ps += __shfl_xor(ps, 8);  ps += __shfl_xor(ps, 16);
        pd += __shfl_xor(pd, 1);  pd += __shfl_xor(pd, 2);  pd += __shfl_xor(pd, 4);
        pd += __shfl_xor(pd, 8);  pd += __shfl_xor(pd, 16);
        if (l32 == 0){
          psumS[(jb + q)*2 + wn] = ps;
          psumD[(jb + q)*2 + wn] = pd;
        }
      }
      const int orow = wn*32 + l32;
      const int slot = ((jb >> 3) & 7) ^ (orow & 7);
      *(u16x4*)(Tt + orow*128 + slot*16 + (jb & 7)*2) = c4;
    }
  }
  __syncthreads();

  {
    const int o = tid & 63, c = tid >> 6;
    u16x8 val = *(const u16x8*)(Tt + o*128 + ((c ^ (o & 7)) << 4));
    *(u16x8*)((char*)hpz2 + ((size_t)(bh1*256 + (jbase >> 3) + c)*64 + o)*16) = val;
  }
  if (tid < 64){
    float sv = (psumS[tid*2] + psumS[tid*2 + 1]) * LOG2E;   // log2 domain
    float dv = (psumD[tid*2] + psumD[tid*2 + 1]) * LOG2E;
    srcv[(size_t)bh1*NSEQ + jbase + tid] = sv;
    dstv[(size_t)bh1*NSEQ + jbase + tid] = dv;
    float dmx = dv;
    dmx = fmaxf(dmx, __shfl_xor(dmx, 1));  dmx = fmaxf(dmx, __shfl_xor(dmx, 2));
    dmx = fmaxf(dmx, __shfl_xor(dmx, 4));  dmx = fmaxf(dmx, __shfl_xor(dmx, 8));
    dmx = fmaxf(dmx, __shfl_xor(dmx, 16)); dmx = fmaxf(dmx, __shfl_xor(dmx, 32));
    if (tid == 0) atomicMax(&dmaxe[bh1], fenc(dmx));
  }
}

// ---------------------------------------------------------------------------
// Kernel B (r9 body, unchanged): register-direct P, linear H staging.
// ---------------------------------------------------------------------------
__global__ __launch_bounds__(512, 4) void k_attn(
    const unsigned short* __restrict__ hpz2, const float* __restrict__ srcv,
    const float* __restrict__ dstv, const unsigned* __restrict__ dmaxe,
    const float* __restrict__ bias, float* __restrict__ out)
{
  __shared__ __align__(16) char smem[33792];   // H0@0, H1@16384, Lbuf@32768
  float* Lbuf = (float*)(smem + 32768);        // [8][32]

  const int tid = threadIdx.x;
  const int bid = blockIdx.x;
  const int bh  = (bid & 7) | (((bid >> 3) & 1) << 3);
  const int i0  = (bid >> 4) << 6;
  const int wave = tid >> 6, lane = tid & 63;
  const int wm = wave & 1, jw = wave >> 1;
  const int l32 = lane & 31, h32 = lane >> 5;

  const float s2  = srcv[(size_t)bh*NSEQ + i0 + wm*32 + l32];
  const float dm2 = fdec(dmaxe[bh]);
  float m2 = s2 + dm2; m2 = fmaxf(m2, 0.2f*m2);   // exact row max (lrelu monotone)
  const float u_ = s2 - m2;            // lrelu(s+d)-m = max(u_+d, fma(0.2,d,v_))
  const float v_ = 0.2f*s2 - m2;
  const float* dptr = dstv + (size_t)bh*NSEQ;

  const u16x8* gp = (const u16x8*)((const char*)hpz2 + (size_t)bh*256*64*16);

  f32x16 accO0 = {0,0,0,0,0,0,0,0,0,0,0,0,0,0,0,0};
  f32x16 accO1 = {0,0,0,0,0,0,0,0,0,0,0,0,0,0,0,0};
  float lpart = 0.f;

  *(u16x8*)(smem + tid*16)         = gp[tid];
  *(u16x8*)(smem + (tid + 512)*16) = gp[tid + 512];
  __syncthreads();

  for (int w = 0; w < 16; ++w){
    char* cur = smem + (w & 1)*16384;
    char* nxt = smem + ((w + 1) & 1)*16384;
    u16x8 r0, r1;
    if (w < 15){
      r0 = gp[(w+1)*1024 + tid];
      r1 = gp[(w+1)*1024 + tid + 512];
    }
    #pragma unroll
    for (int stl = 0; stl < 2; ++stl){
      const int Jl = jw*4 + stl*2 + h32;
      const int j0 = (w*16 + Jl)*8;
      float4 d0 = *(const float4*)(dptr + j0);
      float4 d1 = *(const float4*)(dptr + j0 + 4);
      float e0,e1,e2,e3,e4,e5,e6,e7;
      e0 = fexp2(fmaxf(u_ + d0.x, fmaf(0.2f, d0.x, v_)));
      e1 = fexp2(fmaxf(u_ + d0.y, fmaf(0.2f, d0.y, v_)));
      e2 = fexp2(fmaxf(u_ + d0.z, fmaf(0.2f, d0.z, v_)));
      e3 = fexp2(fmaxf(u_ + d0.w, fmaf(0.2f, d0.w, v_)));
      e4 = fexp2(fmaxf(u_ + d1.x, fmaf(0.2f, d1.x, v_)));
      e5 = fexp2(fmaxf(u_ + d1.y, fmaf(0.2f, d1.y, v_)));
      e6 = fexp2(fmaxf(u_ + d1.z, fmaf(0.2f, d1.z, v_)));
      e7 = fexp2(fmaxf(u_ + d1.w, fmaf(0.2f, d1.w, v_)));
      lpart += ((e0+e1)+(e2+e3)) + ((e4+e5)+(e6+e7));
      u32x4 pk;
      pk[0] = pkbf(e0, e1); pk[1] = pkbf(e2, e3);
      pk[2] = pkbf(e4, e5); pk[3] = pkbf(e6, e7);
      const bf16x8 pA = __builtin_bit_cast(bf16x8, pk);
      const bf16x8 bv0 = *(const bf16x8*)(cur + (Jl*64 +      l32)*16);
      const bf16x8 bv1 = *(const bf16x8*)(cur + (Jl*64 + 32 + l32)*16);
      accO0 = __builtin_amdgcn_mfma_f32_32x32x16_bf16(pA, bv0, accO0, 0, 0, 0);
      accO1 = __builtin_amdgcn_mfma_f32_32x32x16_bf16(pA, bv1, accO1, 0, 0, 0);
    }
    if (w < 15){
      *(u16x8*)(nxt + tid*16)         = r0;
      *(u16x8*)(nxt + (tid + 512)*16) = r1;
    }
    __syncthreads();
  }

  lpart += __shfl_xor(lpart, 32);
  if (lane < 32) Lbuf[(wm*4 + jw)*32 + l32] = lpart;

  const float4 bia = *(const float4*)(bias + (tid & 15)*4);
  #pragma unroll
  for (int ph = 0; ph < 2; ++ph){
    __syncthreads();
    if (wm == ph){
      float* ob = (float*)smem;            // [jw][m 32][o 64] fp32 = 32 KB
      #pragma unroll
      for (int reg = 0; reg < 16; ++reg){
        const int m = (reg & 3) + 8*(reg >> 2) + 4*h32;
        ob[(jw*32 + m)*64 +      l32] = accO0[reg];
        ob[(jw*32 + m)*64 + 32 + l32] = accO1[reg];
      }
    }
    __syncthreads();
    {
      const int i = tid >> 4, o4 = (tid & 15)*4;
      const float* ob = (const float*)smem;
      float4 v0 = *(const float4*)(ob + (0*32 + i)*64 + o4);
      float4 v1 = *(const float4*)(ob + (1*32 + i)*64 + o4);
      float4 v2 = *(const float4*)(ob + (2*32 + i)*64 + o4);
      float4 v3 = *(const float4*)(ob + (3*32 + i)*64 + o4);
      const float l = Lbuf[(ph*4+0)*32 + i] + Lbuf[(ph*4+1)*32 + i]
                    + Lbuf[(ph*4+2)*32 + i] + Lbuf[(ph*4+3)*32 + i];
      const float r = 1.f / l;             // l >= 1 (exp2(0) term present)
      float4 res;
      res.x = (v0.x + v1.x + v2.x + v3.x)*r + bia.x;
      res.y = (v0.y + v1.y + v2.y + v3.y)*r + bia.y;
      res.z = (v0.z + v1.z + v2.z + v3.z)*r + bia.z;
      res.w = (v0.w + v1.w + v2.w + v3.w)*r + bia.w;
      *(float4*)(out + ((size_t)bh*NSEQ + i0 + ph*32 + i)*64 + o4) = res;
    }
  }
}

// ---------------------------------------------------------------------------
// MEASUREMENT ROUND: run the identical pipeline TWICE (idempotent).
// dur_r10 - dur_r9 = warm-path kernel time, discriminating
// "kernels are slow" (H1) vs "harness overhead dominates" (H2).
// ---------------------------------------------------------------------------
extern "C" void kernel_launch(void* const* d_in, const int* in_sizes, int n_in,
                              void* d_out, int out_size, void* d_ws, size_t ws_size,
                              hipStream_t stream)
{
  const float* h     = (const float*)d_in[0];
  const float* w     = (const float*)d_in[1];
  const float* a_src = (const float*)d_in[2];
  const float* a_dst = (const float*)d_in[3];
  const float* bias  = (const float*)d_in[4];
  float* out = (float*)d_out;

  char* ws = (char*)d_ws;
  unsigned short* hpz2 = (unsigned short*)ws;                           // 4 MB bf16 chunk-linear [16][256][64]
  float* srcv = (float*)(ws + (4u<<20));                                // 128 KB (log2-scaled)
  float* dstv = (float*)(ws + (4u<<20) + (128u<<10));                   // 128 KB (log2-scaled)
  unsigned short* wp = (unsigned short*)(ws + (4u<<20) + (256u<<10));   // 384 KB
  unsigned* dmaxe = (unsigned*)(ws + (4u<<20) + (640u<<10));            // 64 B

  for (int rep = 0; rep < 2; ++rep){
    k_prep_w<<<48, 512, 0, stream>>>(w, wp, dmaxe);
    k_hprime<<<512, 512, 0, stream>>>(h, wp, a_src, a_dst, hpz2, srcv, dstv, dmaxe);
    k_attn<<<512, 512, 0, stream>>>(hpz2, srcv, dstv, dmaxe, bias, out);
  }
}

// Round 11
// 119.346 us; speedup vs baseline: 1.4992x; 1.4992x over previous
//
#include <hip/hip_runtime.h>
#include <hip/hip_bf16.h>

#define NHEAD 4
#define FIN   768
#define FOUT  64
#define BSZ   4
#define NSEQ  2048
#define BH    (BSZ*NHEAD)
#define LOG2E 1.44269504088896f

typedef __attribute__((ext_vector_type(8)))  short bf16x8;   // MFMA A/B frag
typedef __attribute__((ext_vector_type(16))) float f32x16;   // MFMA 32x32 C/D
typedef __attribute__((ext_vector_type(8)))  unsigned short u16x8;
typedef __attribute__((ext_vector_type(4)))  unsigned short u16x4;
typedef __attribute__((ext_vector_type(4)))  unsigned u32x4;

__device__ __forceinline__ unsigned short f2bf(float f){
  unsigned b = __float_as_uint(f);
  return (unsigned short)((b + 0x7fffu + ((b >> 16) & 1u)) >> 16);
}
__device__ __forceinline__ float fexp2(float x){
#if __has_builtin(__builtin_amdgcn_exp2f)
  return __builtin_amdgcn_exp2f(x);
#else
  return exp2f(x);
#endif
}
__device__ __forceinline__ unsigned pkbf(float lo, float hi){
#if __has_builtin(__builtin_amdgcn_cvt_pk_bf16_f32)
  typedef __attribute__((ext_vector_type(2))) __bf16 bf2;
  union { bf2 v; unsigned u; } cv;
  cv.v = __builtin_amdgcn_cvt_pk_bf16_f32(lo, hi);
  return cv.u;
#else
  return (unsigned)f2bf(lo) | ((unsigned)f2bf(hi) << 16);
#endif
}

// ---------------------------------------------------------------------------
// Kernel A: h' = h @ w_head via 32x32x16 MFMA. A AND B staged from fp32 with
// inline convert (no prep kernel, no wp image). Double-buffered, ONE barrier
// per K-iter. XCD swizzle: bh1 = (bid&7)|(((bid>>3)&1)<<3) -> each XCD uses
// one head's w (196 KB, L2-resident) and keeps hpz2[bh] home.
// ---------------------------------------------------------------------------
__global__ __launch_bounds__(512, 2) void k_hprime(
    const float* __restrict__ h, const float* __restrict__ w,
    const float* __restrict__ a_src, const float* __restrict__ a_dst,
    unsigned short* __restrict__ hpz2, float* __restrict__ srcv,
    float* __restrict__ dstv)
{
  __shared__ __align__(16) char smem[65536];
  // A0@0, A1@16384, B0@32768, B1@49152
  // epilogue overlays: scratch@0 (16K), psumS@16384, psumD@16896, Tt@32768 (8K)
  float* psumS = (float*)(smem + 16384);
  float* psumD = (float*)(smem + 16896);
  char*  Tt    = smem + 32768;

  const int tid  = threadIdx.x;
  const int bid  = blockIdx.x;
  const int bh1  = (bid & 7) | (((bid >> 3) & 1) << 3);
  const int head = bh1 & 3;
  const int jbase = (bid >> 4) << 6;                 // within-sequence row base
  const int i0a   = (bh1 >> 2)*NSEQ + jbase;         // global flat row
  const int wave = tid >> 6, lane = tid & 63;
  const int wm = wave & 1, wn = (wave >> 1) & 1, kw = wave >> 2;
  const int l32 = lane & 31, h32 = lane >> 5;

  f32x16 acc = {0,0,0,0,0,0,0,0,0,0,0,0,0,0,0,0};

  // A staging map: row sr, chunk sc (r9-proven)
  const int sr = tid >> 3, sc = tid & 7;
  const float* hA = h + (size_t)(i0a + sr)*FIN + sc*8;
  const int aslot = (sc ^ (sr & 7)) << 4;

  // B staging map: o = lane (coalesced), halves g0 = cc, g1 = cc+8
  const int ob = tid & 63, cc = tid >> 6;
  const float* wsrc = w + (size_t)head*FIN*FOUT + ob;   // + f*64
  const int bslot0 = ((cc & 7) ^ (ob & 7)) << 4;        // half 0 slot
  // half 1 chunk-in-half = cc as well (g1&7 == cc)

  // prologue: prefetch iter 0
  float4 ra0 = *(const float4*)(hA);
  float4 ra1 = *(const float4*)(hA + 4);
  float4 ra2 = *(const float4*)(hA + 64);
  float4 ra3 = *(const float4*)(hA + 68);
  float rb[16];
  #pragma unroll
  for (int j = 0; j < 8; ++j){
    rb[j]     = wsrc[(size_t)(cc*8 + j)*FOUT];          // g0 = cc   (k 0..63)
    rb[8 + j] = wsrc[(size_t)(64 + cc*8 + j)*FOUT];     // g1 = cc+8 (k 64..127)
  }

  for (int it = 0; it < 6; ++it){
    char* Ab = smem +         (it & 1)*16384;
    char* Bb = smem + 32768 + (it & 1)*16384;
    u32x4 pk0, pk1;
    pk0[0] = pkbf(ra0.x, ra0.y); pk0[1] = pkbf(ra0.z, ra0.w);
    pk0[2] = pkbf(ra1.x, ra1.y); pk0[3] = pkbf(ra1.z, ra1.w);
    pk1[0] = pkbf(ra2.x, ra2.y); pk1[1] = pkbf(ra2.z, ra2.w);
    pk1[2] = pkbf(ra3.x, ra3.y); pk1[3] = pkbf(ra3.z, ra3.w);
    *(u32x4*)(Ab + sr*256 + aslot)        = pk0;
    *(u32x4*)(Ab + sr*256 + 128 + aslot)  = pk1;
    u32x4 qb0, qb1;
    qb0[0] = pkbf(rb[0],  rb[1]);  qb0[1] = pkbf(rb[2],  rb[3]);
    qb0[2] = pkbf(rb[4],  rb[5]);  qb0[3] = pkbf(rb[6],  rb[7]);
    qb1[0] = pkbf(rb[8],  rb[9]);  qb1[1] = pkbf(rb[10], rb[11]);
    qb1[2] = pkbf(rb[12], rb[13]); qb1[3] = pkbf(rb[14], rb[15]);
    *(u32x4*)(Bb + ob*256 +       bslot0) = qb0;
    *(u32x4*)(Bb + ob*256 + 128 + bslot0) = qb1;
    __syncthreads();                       // single barrier per iter (dbuf)
    if (it < 5){
      const float* an = hA + (it+1)*128;
      ra0 = *(const float4*)(an);      ra1 = *(const float4*)(an + 4);
      ra2 = *(const float4*)(an + 64); ra3 = *(const float4*)(an + 68);
      const float* wn_ = wsrc + (size_t)(it+1)*128*FOUT;
      #pragma unroll
      for (int j = 0; j < 8; ++j){
        rb[j]     = wn_[(size_t)(cc*8 + j)*FOUT];
        rb[8 + j] = wn_[(size_t)(64 + cc*8 + j)*FOUT];
      }
    }
    #pragma unroll
    for (int s = 0; s < 4; ++s){
      const int slot = (((s*2 + h32) ^ (l32 & 7)) << 4);
      bf16x8 av = *(const bf16x8*)(Ab + (wm*32 + l32)*256 + kw*128 + slot);
      bf16x8 bv = *(const bf16x8*)(Bb + (wn*32 + l32)*256 + kw*128 + slot);
      acc = __builtin_amdgcn_mfma_f32_32x32x16_bf16(av, bv, acc, 0, 0, 0);
    }
  }

  // kw-merge via scratch@0 (A0 region; disjoint from iter-5's A1/B1 reads)
  if (kw == 1) *(f32x16*)(smem + (size_t)((wave & 3)*64 + lane)*64) = acc;
  __syncthreads();
  if (kw == 0){
    acc += *(const f32x16*)(smem + (size_t)((wave & 3)*64 + lane)*64);
    const float as = a_src[head*64 + wn*32 + l32];
    const float ad = a_dst[head*64 + wn*32 + l32];
    #pragma unroll
    for (int rb2 = 0; rb2 < 4; ++rb2){
      const int jb = wm*32 + rb2*8 + h32*4;
      u16x4 c4;
      #pragma unroll
      for (int q = 0; q < 4; ++q){
        const float v = acc[rb2*4 + q];
        c4[q] = f2bf(v);
        const float t = tanhf(v);
        float ps = t*as, pd = t*ad;
        ps += __shfl_xor(ps, 1);  ps += __shfl_xor(ps, 2);  ps += __shfl_xor(ps, 4);
        ps += __shfl_xor(ps, 8);  ps += __shfl_xor(ps, 16);
        pd += __shfl_xor(pd, 1);  pd += __shfl_xor(pd, 2);  pd += __shfl_xor(pd, 4);
        pd += __shfl_xor(pd, 8);  pd += __shfl_xor(pd, 16);
        if (l32 == 0){
          psumS[(jb + q)*2 + wn] = ps;
          psumD[(jb + q)*2 + wn] = pd;
        }
      }
      const int orow = wn*32 + l32;
      const int slot = ((jb >> 3) & 7) ^ (orow & 7);
      *(u16x4*)(Tt + orow*128 + slot*16 + (jb & 7)*2) = c4;
    }
  }
  __syncthreads();

  {
    const int o = tid & 63, c = tid >> 6;
    u16x8 val = *(const u16x8*)(Tt + o*128 + ((c ^ (o & 7)) << 4));
    *(u16x8*)((char*)hpz2 + ((size_t)(bh1*256 + (jbase >> 3) + c)*64 + o)*16) = val;
  }
  if (tid < 64){
    // log2-domain pre-scale; NO max subtraction needed downstream (bounded
    // inputs: |s|,|d| <= ~28.1 in log2 units -> exp2 range fp32-safe)
    srcv[(size_t)bh1*NSEQ + jbase + tid] = (psumS[tid*2] + psumS[tid*2 + 1]) * LOG2E;
    dstv[(size_t)bh1*NSEQ + jbase + tid] = (psumD[tid*2] + psumD[tid*2 + 1]) * LOG2E;
  }
}

// ---------------------------------------------------------------------------
// Kernel B: register-direct P, linear H staging, NO softmax-max (scale-
// invariant: p = exp2(lrelu(s+d)), l = sum p, out = acc/l).
// ---------------------------------------------------------------------------
__global__ __launch_bounds__(512, 4) void k_attn(
    const unsigned short* __restrict__ hpz2, const float* __restrict__ srcv,
    const float* __restrict__ dstv, const float* __restrict__ bias,
    float* __restrict__ out)
{
  __shared__ __align__(16) char smem[33792];   // H0@0, H1@16384, Lbuf@32768
  float* Lbuf = (float*)(smem + 32768);        // [8][32]

  const int tid = threadIdx.x;
  const int bid = blockIdx.x;
  const int bh  = (bid & 7) | (((bid >> 3) & 1) << 3);
  const int i0  = (bid >> 4) << 6;
  const int wave = tid >> 6, lane = tid & 63;
  const int wm = wave & 1, jw = wave >> 1;
  const int l32 = lane & 31, h32 = lane >> 5;

  const float s2 = srcv[(size_t)bh*NSEQ + i0 + wm*32 + l32];
  const float u_ = s2;                 // lrelu(s+d) = max(u_+d, 0.2d+v_)
  const float v_ = 0.2f*s2;
  const float* dptr = dstv + (size_t)bh*NSEQ;

  const u16x8* gp = (const u16x8*)((const char*)hpz2 + (size_t)bh*256*64*16);

  f32x16 accO0 = {0,0,0,0,0,0,0,0,0,0,0,0,0,0,0,0};
  f32x16 accO1 = {0,0,0,0,0,0,0,0,0,0,0,0,0,0,0,0};
  float lpart = 0.f;

  *(u16x8*)(smem + tid*16)         = gp[tid];
  *(u16x8*)(smem + (tid + 512)*16) = gp[tid + 512];
  __syncthreads();

  for (int w = 0; w < 16; ++w){
    char* cur = smem + (w & 1)*16384;
    char* nxt = smem + ((w + 1) & 1)*16384;
    u16x8 r0, r1;
    if (w < 15){
      r0 = gp[(w+1)*1024 + tid];
      r1 = gp[(w+1)*1024 + tid + 512];
    }
    #pragma unroll
    for (int stl = 0; stl < 2; ++stl){
      const int Jl = jw*4 + stl*2 + h32;
      const int j0 = (w*16 + Jl)*8;
      float4 d0 = *(const float4*)(dptr + j0);
      float4 d1 = *(const float4*)(dptr + j0 + 4);
      float e0,e1,e2,e3,e4,e5,e6,e7;
      e0 = fexp2(fmaxf(u_ + d0.x, fmaf(0.2f, d0.x, v_)));
      e1 = fexp2(fmaxf(u_ + d0.y, fmaf(0.2f, d0.y, v_)));
      e2 = fexp2(fmaxf(u_ + d0.z, fmaf(0.2f, d0.z, v_)));
      e3 = fexp2(fmaxf(u_ + d0.w, fmaf(0.2f, d0.w, v_)));
      e4 = fexp2(fmaxf(u_ + d1.x, fmaf(0.2f, d1.x, v_)));
      e5 = fexp2(fmaxf(u_ + d1.y, fmaf(0.2f, d1.y, v_)));
      e6 = fexp2(fmaxf(u_ + d1.z, fmaf(0.2f, d1.z, v_)));
      e7 = fexp2(fmaxf(u_ + d1.w, fmaf(0.2f, d1.w, v_)));
      lpart += ((e0+e1)+(e2+e3)) + ((e4+e5)+(e6+e7));
      u32x4 pk;
      pk[0] = pkbf(e0, e1); pk[1] = pkbf(e2, e3);
      pk[2] = pkbf(e4, e5); pk[3] = pkbf(e6, e7);
      const bf16x8 pA = __builtin_bit_cast(bf16x8, pk);
      const bf16x8 bv0 = *(const bf16x8*)(cur + (Jl*64 +      l32)*16);
      const bf16x8 bv1 = *(const bf16x8*)(cur + (Jl*64 + 32 + l32)*16);
      accO0 = __builtin_amdgcn_mfma_f32_32x32x16_bf16(pA, bv0, accO0, 0, 0, 0);
      accO1 = __builtin_amdgcn_mfma_f32_32x32x16_bf16(pA, bv1, accO1, 0, 0, 0);
    }
    if (w < 15){
      *(u16x8*)(nxt + tid*16)         = r0;
      *(u16x8*)(nxt + (tid + 512)*16) = r1;
    }
    __syncthreads();
  }

  lpart += __shfl_xor(lpart, 32);
  if (lane < 32) Lbuf[(wm*4 + jw)*32 + l32] = lpart;

  const float4 bia = *(const float4*)(bias + (tid & 15)*4);
  #pragma unroll
  for (int ph = 0; ph < 2; ++ph){
    __syncthreads();
    if (wm == ph){
      float* ob = (float*)smem;            // [jw][m 32][o 64] fp32 = 32 KB
      #pragma unroll
      for (int reg = 0; reg < 16; ++reg){
        const int m = (reg & 3) + 8*(reg >> 2) + 4*h32;
        ob[(jw*32 + m)*64 +      l32] = accO0[reg];
        ob[(jw*32 + m)*64 + 32 + l32] = accO1[reg];
      }
    }
    __syncthreads();
    {
      const int i = tid >> 4, o4 = (tid & 15)*4;
      const float* ob = (const float*)smem;
      float4 v0 = *(const float4*)(ob + (0*32 + i)*64 + o4);
      float4 v1 = *(const float4*)(ob + (1*32 + i)*64 + o4);
      float4 v2 = *(const float4*)(ob + (2*32 + i)*64 + o4);
      float4 v3 = *(const float4*)(ob + (3*32 + i)*64 + o4);
      const float l = Lbuf[(ph*4+0)*32 + i] + Lbuf[(ph*4+1)*32 + i]
                    + Lbuf[(ph*4+2)*32 + i] + Lbuf[(ph*4+3)*32 + i];
      const float r = 1.f / l;
      float4 res;
      res.x = (v0.x + v1.x + v2.x + v3.x)*r + bia.x;
      res.y = (v0.y + v1.y + v2.y + v3.y)*r + bia.y;
      res.z = (v0.z + v1.z + v2.z + v3.z)*r + bia.z;
      res.w = (v0.w + v1.w + v2.w + v3.w)*r + bia.w;
      *(float4*)(out + ((size_t)bh*NSEQ + i0 + ph*32 + i)*64 + o4) = res;
    }
  }
}

// ---------------------------------------------------------------------------
extern "C" void kernel_launch(void* const* d_in, const int* in_sizes, int n_in,
                              void* d_out, int out_size, void* d_ws, size_t ws_size,
                              hipStream_t stream)
{
  const float* h     = (const float*)d_in[0];
  const float* w     = (const float*)d_in[1];
  const float* a_src = (const float*)d_in[2];
  const float* a_dst = (const float*)d_in[3];
  const float* bias  = (const float*)d_in[4];
  float* out = (float*)d_out;

  char* ws = (char*)d_ws;
  unsigned short* hpz2 = (unsigned short*)ws;                 // 4 MB bf16 chunk-linear
  float* srcv = (float*)(ws + (4u<<20));                      // 128 KB (log2-scaled)
  float* dstv = (float*)(ws + (4u<<20) + (128u<<10));         // 128 KB (log2-scaled)

  k_hprime<<<512, 512, 0, stream>>>(h, w, a_src, a_dst, hpz2, srcv, dstv);
  k_attn<<<512, 512, 0, stream>>>(hpz2, srcv, dstv, bias, out);
}